// Round 4
// baseline (975.091 us; speedup 1.0000x reference)
//
#include <hip/hip_runtime.h>

typedef __attribute__((ext_vector_type(8))) short bf16x8;
typedef __attribute__((ext_vector_type(4))) float floatx4;
typedef __attribute__((ext_vector_type(4))) unsigned int uintx4;

#define EPSF 1e-5f
#define RS512 0.04419417382415922f /* 1/sqrt(512) */

__device__ __forceinline__ unsigned short f2bf(float f) {
  unsigned int u = __float_as_uint(f);
  u += 0x7fffu + ((u >> 16) & 1u);
  return (unsigned short)(u >> 16);
}

union BFrag { bf16x8 v; int i[4]; unsigned short s[8]; };

// async global -> LDS, 16B per lane. LDS dest is wave-uniform base + lane*16;
// global src is per-lane (lets us swizzle V's placement at the source).
__device__ __forceinline__ void gll16(const void* g, void* l) {
  __builtin_amdgcn_global_load_lds(
      (__attribute__((address_space(1))) void*)g,
      (__attribute__((address_space(3))) void*)l, 16, 0, 0);
}

// ---------------- Kernel 1: fused qkv conv + BN + PReLU, bf16 emit ----------
// (unchanged from R3)
__global__ __launch_bounds__(512) void qkv_kernel(
    const float* __restrict__ x,
    const float* __restrict__ Wq, const float* __restrict__ bq,
    const float* __restrict__ gq, const float* __restrict__ beq,
    const float* __restrict__ mq, const float* __restrict__ vq,
    const float* __restrict__ aq,
    unsigned short* __restrict__ Q, unsigned short* __restrict__ K,
    unsigned short* __restrict__ V) {
  const int b = blockIdx.y;
  const int t0 = blockIdx.x << 4;
  const int tid = threadIdx.x;

  __shared__ unsigned short xs[16 * 1032];
  __shared__ float sW[1584];  // [n][ch][33] folded (pitch 33: conflict-free)
  __shared__ float sB[48];
  __shared__ unsigned short vsm[512 * 18];

  for (int idx = tid; idx < 1536; idx += 512) {
    int n = idx >> 9, ch = (idx >> 5) & 15;
    float inv = gq[n * 16 + ch] * rsqrtf(vq[n * 16 + ch] + EPSF);
    if (n == 1) inv *= RS512;
    sW[n * 528 + ch * 33 + (idx & 31)] = Wq[idx] * inv;
  }
  if (tid < 48) {
    int n = tid >> 4;
    float inv = gq[tid] * rsqrtf(vq[tid] + EPSF);
    float bb = (bq[tid] - mq[tid]) * inv + beq[tid];
    if (n == 1) bb *= RS512;
    sB[tid] = bb;
  }
  {
    int tq = tid & 3, rq = tid >> 2;
    const float* xb = x + (size_t)b * 1024 * 4000 + t0 + (tq << 2);
    for (int rr = rq; rr < 1024; rr += 128) {
      float4 f = *(const float4*)(xb + (size_t)rr * 4000);
      xs[(tq * 4 + 0) * 1032 + rr] = f2bf(f.x);
      xs[(tq * 4 + 1) * 1032 + rr] = f2bf(f.y);
      xs[(tq * 4 + 2) * 1032 + rr] = f2bf(f.z);
      xs[(tq * 4 + 3) * 1032 + rr] = f2bf(f.w);
    }
  }
  __syncthreads();

  const int lane = tid & 63, w = tid >> 6;
  const int c = lane & 15, qd = lane >> 4;
  const int wg = w >> 2;
  const int lt = (w & 3) * 4 + qd;
  const int t = t0 + lt;
  const int f0 = (c & 3) * 8;
  const unsigned short* xrow = xs + lt * 1032;
  const float aQ = aq[0], aK = aq[1], aV = aq[2];

  for (int p = 0; p < 2; ++p) {
    const int pp = p + (wg << 1);
    const int ch = (c >> 2) + (pp << 2);
    float acq[8], ack[8], acv[8];
#pragma unroll
    for (int j = 0; j < 8; ++j) {
      acq[j] = sB[ch]; ack[j] = sB[16 + ch]; acv[j] = sB[32 + ch];
    }
    const float* wqp = sW + ch * 33;
    const float* wkp = sW + 528 + ch * 33;
    const float* wvp = sW + 1056 + ch * 33;
    for (int i = 0; i < 32; ++i) {
      BFrag xf;
      xf.v = *(const bf16x8*)(xrow + i * 32 + f0);
      float wqi = wqp[i], wki = wkp[i], wvi2 = wvp[i];
#pragma unroll
      for (int j = 0; j < 8; ++j) {
        float xv = __uint_as_float((unsigned int)xf.s[j] << 16);
        acq[j] += wqi * xv; ack[j] += wki * xv; acv[j] += wvi2 * xv;
      }
    }
    unsigned int qw[4], kw[4];
#pragma unroll
    for (int j2 = 0; j2 < 4; ++j2) {
      float q0 = acq[2 * j2], q1 = acq[2 * j2 + 1];
      q0 = q0 > 0.f ? q0 : aQ * q0; q1 = q1 > 0.f ? q1 : aQ * q1;
      qw[j2] = (unsigned int)f2bf(q0) | ((unsigned int)f2bf(q1) << 16);
      float k0 = ack[2 * j2], k1 = ack[2 * j2 + 1];
      k0 = k0 > 0.f ? k0 : aK * k0; k1 = k1 > 0.f ? k1 : aK * k1;
      kw[j2] = (unsigned int)f2bf(k0) | ((unsigned int)f2bf(k1) << 16);
    }
    const int d0 = (pp << 7) + (c << 3);
    uintx4 qv, kv;
    qv[0] = qw[0]; qv[1] = qw[1]; qv[2] = qw[2]; qv[3] = qw[3];
    kv[0] = kw[0]; kv[1] = kw[1]; kv[2] = kw[2]; kv[3] = kw[3];
    *(uintx4*)(Q + (size_t)(b * 4000 + t) * 512 + d0) = qv;
    *(uintx4*)(K + (size_t)(b * 4000 + t) * 512 + d0) = kv;
#pragma unroll
    for (int j = 0; j < 8; ++j) {
      float v0 = acv[j];
      v0 = v0 > 0.f ? v0 : aV * v0;
      vsm[(d0 + j) * 18 + lt] = f2bf(v0);
    }
  }
  __syncthreads();
  {
    const int st = t0 >> 5;
    const int toff = t0 & 16;
    unsigned short* vt = V + ((size_t)(b * 125 + st) * 512) * 32 + toff;
    for (int i = tid; i < 4096; i += 512) {
      int d = i >> 3, u = i & 7;
      unsigned int w2 = *(unsigned int*)&vsm[d * 18 + 2 * u];
      ((unsigned int*)(vt + d * 32))[u] = w2;
    }
  }
}

// ---------------- Kernel 2: fat-wave sigmoid-attention + enc ConvBlock ------
// 512 threads = 8 waves = 4 q-groups x 2 s-halves over 64-s tiles (63 tiles).
// S-phase: wave (qg,sg) computes S for 32 q x 32 s; Q streamed from L2
// (XCD-pinned by b), K read from LDS once per k-step feeding both q-subtiles
// -> K LDS reads halved vs 16q waves. P[128][72] bf16 in LDS.
// PV-phase: d-split as before (wave w owns d[64w,64w+64) for all 128 q).
// Single-buffered K and V with counted overlap: K_{i+1} staged during PV_i,
// V_i staged during S_i. Two barriers per 64-s tile.
__global__ __launch_bounds__(512, 2) void attn_kernel(
    const float* __restrict__ x,
    const float* __restrict__ encW, const float* __restrict__ encb,
    const float* __restrict__ encg, const float* __restrict__ encbe,
    const float* __restrict__ encm, const float* __restrict__ encv,
    const float* __restrict__ enca,
    const unsigned short* __restrict__ Q, const unsigned short* __restrict__ K,
    const unsigned short* __restrict__ V, float* __restrict__ out) {
  const int tid = threadIdx.x;
  const int lane = tid & 63;
  const int w = tid >> 6;
  const int b = blockIdx.x & 7;            // XCD-pinned: one b per XCD
  const int bt0 = (blockIdx.x >> 3) << 7;  // 0..3968
  const int t0 = bt0 + (w << 4);
  const bool active = t0 < 4000;
  const int c = lane & 15, qd = lane >> 4;

  // LDS: Ks[64][520] 66560B | Vs[512][64] 65536B (granule-swizzled) |
  //      Pb[128][72] 18432B  = 150528 B. Eb f32[64][516]=132096B overlays Ks+Vs.
  __shared__ __align__(16) unsigned char smem[150528];
  unsigned short* Ksb = (unsigned short*)smem;
  unsigned short* Vsb = Ksb + 64 * 520;
  unsigned short* Pb = Vsb + 512 * 64;
  float* Eb = (float*)smem;

  floatx4 acc[4][8];
#pragma unroll
  for (int m = 0; m < 4; ++m)
#pragma unroll
    for (int q2 = 0; q2 < 8; ++q2) {
      acc[m][q2][0] = 0.f; acc[m][q2][1] = 0.f;
      acc[m][q2][2] = 0.f; acc[m][q2][3] = 0.f;
    }

  const unsigned short* Qg = Q + (size_t)b * 4000 * 512;
  const unsigned short* Kb = K + (size_t)b * 4000 * 512;
  const unsigned short* Vb = V + (size_t)b * 125 * 16384;

  const int qg = w & 3, sg = w >> 2;
  // loop-invariant S-phase pointers (Q clamped for tail blocks)
  int q0i = bt0 + qg * 32 + c;      if (q0i > 3999) q0i = 3999;
  int q1i = bt0 + qg * 32 + 16 + c; if (q1i > 3999) q1i = 3999;
  const unsigned short* qp0 = Qg + (size_t)q0i * 512 + qd * 8;
  const unsigned short* qp1 = Qg + (size_t)q1i * 512 + qd * 8;
  const unsigned short* kp0 = Ksb + (sg * 32 + c) * 520 + qd * 8;
  const unsigned short* kp1 = kp0 + 16 * 520;

  // V staging lane constants: row-within-8 vro, phys slot lane&7 sources
  // logical slot (lane&7)^(vro&7); logical slot>=4 -> second 32-token tile.
  const int vkl = (lane & 7) ^ ((lane >> 3) & 7);
  const int vth = vkl >> 2;
  const int vro = lane >> 3;
  const int vco = (vkl & 3) * 8;

  // P write base: row (qg*32 [+qt*16] + c), col (sg*32 [+st*16] + qd*4)
  unsigned short* pw0 = Pb + (qg * 32 + c) * 72 + sg * 32 + qd * 4;

  auto stageK = [&](int it) {
    const int rr = w << 3;
#pragma unroll
    for (int j = 0; j < 8; ++j) {
      int t = it * 64 + rr + j; if (t > 3999) t = 3999;
      gll16(Kb + (size_t)t * 512 + lane * 8, Ksb + (rr + j) * 520);
    }
  };
  auto stageV = [&](int it) {
    int ti = it * 2 + vth; if (ti > 124) ti = 124;
    const unsigned short* src = Vb + (size_t)ti * 16384 + vro * 32 + vco;
    unsigned short* dst = Vsb + (w << 12);
#pragma unroll
    for (int j = 0; j < 8; ++j)
      gll16(src + ((w << 3) + j) * 256, dst + (j << 9));
  };

  stageK(0);

#pragma unroll 1
  for (int it = 0; it < 63; ++it) {
    asm volatile("s_waitcnt vmcnt(0)" ::: "memory");  // K_it landed
    __syncthreads();  // B1: PV_{it-1} done reading Vs/Pb

    // ---- S-phase: 32q x 32s per wave, ks-major, Q streamed, K from LDS ----
    floatx4 s00, s01, s10, s11;
    s00[0] = s00[1] = s00[2] = s00[3] = 0.f;
    s01 = s00; s10 = s00; s11 = s00;
    __builtin_amdgcn_s_setprio(1);
#pragma unroll
    for (int ks = 0; ks < 4; ++ks) {
      bf16x8 a0 = *(const bf16x8*)(qp0 + ks * 32);
      bf16x8 a1 = *(const bf16x8*)(qp1 + ks * 32);
      bf16x8 k0 = *(const bf16x8*)(kp0 + ks * 32);
      bf16x8 k1 = *(const bf16x8*)(kp1 + ks * 32);
      s00 = __builtin_amdgcn_mfma_f32_16x16x32_bf16(k0, a0, s00, 0, 0, 0);
      s01 = __builtin_amdgcn_mfma_f32_16x16x32_bf16(k1, a0, s01, 0, 0, 0);
      s10 = __builtin_amdgcn_mfma_f32_16x16x32_bf16(k0, a1, s10, 0, 0, 0);
      s11 = __builtin_amdgcn_mfma_f32_16x16x32_bf16(k1, a1, s11, 0, 0, 0);
    }
    __builtin_amdgcn_s_setprio(0);
    __builtin_amdgcn_sched_barrier(0);
    stageV(it);  // V_it in flight across rest of S-phase
    __builtin_amdgcn_sched_barrier(0);
    __builtin_amdgcn_s_setprio(1);
#pragma unroll 4
    for (int ks = 4; ks < 16; ++ks) {
      bf16x8 a0 = *(const bf16x8*)(qp0 + ks * 32);
      bf16x8 a1 = *(const bf16x8*)(qp1 + ks * 32);
      bf16x8 k0 = *(const bf16x8*)(kp0 + ks * 32);
      bf16x8 k1 = *(const bf16x8*)(kp1 + ks * 32);
      s00 = __builtin_amdgcn_mfma_f32_16x16x32_bf16(k0, a0, s00, 0, 0, 0);
      s01 = __builtin_amdgcn_mfma_f32_16x16x32_bf16(k1, a0, s01, 0, 0, 0);
      s10 = __builtin_amdgcn_mfma_f32_16x16x32_bf16(k0, a1, s10, 0, 0, 0);
      s11 = __builtin_amdgcn_mfma_f32_16x16x32_bf16(k1, a1, s11, 0, 0, 0);
    }
    __builtin_amdgcn_s_setprio(0);

    {  // sigmoid + pack + P write (4 frags of 4 consecutive-s values)
      const bool sval = (it < 62) || (sg == 0);  // tail: sg=1 half invalid
      floatx4 sa[4] = {s00, s01, s10, s11};
      uint2 z[4];
#pragma unroll
      for (int fgi = 0; fgi < 4; ++fgi) {
        float p0 = __builtin_amdgcn_rcpf(1.f + __expf(-sa[fgi][0]));
        float p1 = __builtin_amdgcn_rcpf(1.f + __expf(-sa[fgi][1]));
        float p2 = __builtin_amdgcn_rcpf(1.f + __expf(-sa[fgi][2]));
        float p3 = __builtin_amdgcn_rcpf(1.f + __expf(-sa[fgi][3]));
        z[fgi].x = sval ? ((unsigned int)f2bf(p0) | ((unsigned int)f2bf(p1) << 16)) : 0u;
        z[fgi].y = sval ? ((unsigned int)f2bf(p2) | ((unsigned int)f2bf(p3) << 16)) : 0u;
      }
      *(uint2*)pw0 = z[0];                 // qt0, st0
      *(uint2*)(pw0 + 16) = z[1];          // qt0, st1
      *(uint2*)(pw0 + 16 * 72) = z[2];     // qt1, st0
      *(uint2*)(pw0 + 16 * 72 + 16) = z[3];
    }

    asm volatile("s_waitcnt vmcnt(0)" ::: "memory");  // V_it landed
    __syncthreads();  // B2: P visible; all K_it reads done
    if (it + 1 < 63) stageK(it + 1);  // flies across PV

    // ---- PV-phase: d-slice [64w,64w+64) for all 128 q, contract 64 s ----
    bf16x8 vf[4][2];
#pragma unroll
    for (int md = 0; md < 4; ++md) {
      const int r = (w << 6) + (md << 4) + c;
#pragma unroll
      for (int k2 = 0; k2 < 2; ++k2)
        vf[md][k2] = *(const bf16x8*)(
            Vsb + (((r << 3) + (((k2 << 2) + qd) ^ (r & 7))) << 3));
    }
    __builtin_amdgcn_s_setprio(1);
#pragma unroll
    for (int k2 = 0; k2 < 2; ++k2)
#pragma unroll
      for (int q2 = 0; q2 < 8; ++q2) {
        bf16x8 pf = *(const bf16x8*)(Pb + ((q2 << 4) + c) * 72 + (k2 << 5) + (qd << 3));
#pragma unroll
        for (int md = 0; md < 4; ++md)
          acc[md][q2] = __builtin_amdgcn_mfma_f32_16x16x32_bf16(
              vf[md][k2], pf, acc[md][q2], 0, 0, 0);
      }
    __builtin_amdgcn_s_setprio(0);
  }

  __syncthreads();  // all K/V/P reads done -> Eb may overlay

  // ---- epilogue: exchange d-sliced acc via Eb, then enc+residual (R3) ----
  const float ealpha = enca[0];
#pragma unroll
  for (int rnd = 0; rnd < 2; ++rnd) {
#pragma unroll
    for (int m = 0; m < 4; ++m)
#pragma unroll
      for (int q2 = 0; q2 < 4; ++q2)
        *(floatx4*)&Eb[((q2 << 4) + c) * 516 + (w << 6) + (m << 4) +
                       (qd << 2)] = acc[m][(rnd << 2) | q2];
    __syncthreads();
    if ((w >> 2) == rnd && active) {
      const float* er = Eb + (((w & 3) << 4) + c) * 516;
#pragma unroll
      for (int hi = 0; hi < 2; ++hi) {
        floatx4 sh[16];
#pragma unroll
        for (int i = 0; i < 16; ++i)
          sh[i] = *(const floatx4*)&er[(i << 5) + (hi << 4) + (qd << 2)];
#pragma unroll 1
        for (int o = 0; o < 32; ++o) {
          float inv = encg[o] * rsqrtf(encv[o] + EPSF);
          float bfo = (encb[o] - encm[o]) * inv + encbe[o];
          float e0 = 0.f, e1 = 0.f, e2 = 0.f, e3 = 0.f;
#pragma unroll
          for (int i = 0; i < 16; ++i) {
            float wi = encW[(o << 4) + i];
            e0 += wi * sh[i][0]; e1 += wi * sh[i][1];
            e2 += wi * sh[i][2]; e3 += wi * sh[i][3];
          }
          float ee[4] = {e0, e1, e2, e3};
#pragma unroll
          for (int rr = 0; rr < 4; ++rr) {
            float e = ee[rr] * inv + bfo;
            e = e > 0.f ? e : ealpha * e;
            int fq = (qd << 2) + rr + (hi << 4);
            size_t idx = ((size_t)((b << 5) + o) * 32 + fq) * 4000 + t0 + c;
            out[idx] = e + x[idx];
          }
        }
      }
    }
    __syncthreads();
  }
}

extern "C" void kernel_launch(void* const* d_in, const int* in_sizes, int n_in,
                              void* d_out, int out_size, void* d_ws,
                              size_t ws_size, hipStream_t stream) {
  const float* x = (const float*)d_in[0];
  unsigned short* Q = (unsigned short*)d_ws;
  unsigned short* K = Q + (size_t)8 * 4000 * 512;
  unsigned short* V = K + (size_t)8 * 4000 * 512;

  dim3 g1(250, 8);
  qkv_kernel<<<g1, 512, 0, stream>>>(
      x, (const float*)d_in[1], (const float*)d_in[2], (const float*)d_in[3],
      (const float*)d_in[4], (const float*)d_in[5], (const float*)d_in[6],
      (const float*)d_in[7], Q, K, V);

  attn_kernel<<<dim3(256), 512, 0, stream>>>(
      x, (const float*)d_in[8], (const float*)d_in[9], (const float*)d_in[10],
      (const float*)d_in[11], (const float*)d_in[12], (const float*)d_in[13],
      (const float*)d_in[14], Q, K, V, (float*)d_out);
}

// Round 5
// 626.902 us; speedup vs baseline: 1.5554x; 1.5554x over previous
//
#include <hip/hip_runtime.h>

typedef __attribute__((ext_vector_type(8))) short bf16x8;
typedef __attribute__((ext_vector_type(4))) float floatx4;
typedef __attribute__((ext_vector_type(4))) unsigned int uintx4;

#define EPSF 1e-5f
#define RS512 0.04419417382415922f /* 1/sqrt(512) */

__device__ __forceinline__ unsigned short f2bf(float f) {
  unsigned int u = __float_as_uint(f);
  u += 0x7fffu + ((u >> 16) & 1u);
  return (unsigned short)(u >> 16);
}

union BFrag { bf16x8 v; int i[4]; unsigned short s[8]; };

// async global -> LDS, 16B per lane. LDS dest is wave-uniform base + lane*16;
// global src is per-lane (lets us swizzle V's placement at the source).
__device__ __forceinline__ void gll16(const void* g, void* l) {
  __builtin_amdgcn_global_load_lds(
      (__attribute__((address_space(1))) void*)g,
      (__attribute__((address_space(3))) void*)l, 16, 0, 0);
}

// ---------------- Kernel 1: MFMA qkv conv + BN + PReLU, bf16 emit -----------
// Per f: out[48ch,16t] = W[48,32c] x x[32c,16t]. A = W as split-precision
// bf16 pair (hi + residual lo) -> two chained MFMAs per tile, f32 accum:
// weight error ~2^-17, far below the existing bf16 rounding of x.
// Per wave (4 f values): 24 MFMA + 4 LDS b128 B-reads replaces ~2300 VALU.
// Q: [8][4000][512] token-major; K: same (pre-scaled 1/sqrt(512));
// V: tiled [8][125][512][32].
__global__ __launch_bounds__(512) void qkv_kernel(
    const float* __restrict__ x,
    const float* __restrict__ Wq, const float* __restrict__ bq,
    const float* __restrict__ gq, const float* __restrict__ beq,
    const float* __restrict__ mq, const float* __restrict__ vq,
    const float* __restrict__ aq,
    unsigned short* __restrict__ Q, unsigned short* __restrict__ K,
    unsigned short* __restrict__ V) {
  const int b = blockIdx.y;
  const int t0 = blockIdx.x << 4;  // 250 blocks: t0 in [0,4000)
  const int tid = threadIdx.x;

  // smem map (phase 1/2): xs2 bf16 [f=32][t=16][c pitch 40] @0 (41472 B),
  //   sWf f32 [48][32] @41472 (6144 B), sWA bf16 [6][64][8] @47616 (6144 B).
  // epilogue overlay: oQ [16][520] @0, oK [16][520] @16640B, oV [512][18].
  // per-f pitch 648 shorts => f stride 324 words (mod 32 = 4): staging writes
  // spread banks; t pitch 40 shorts keeps b128 reads 16B-aligned.
  __shared__ __align__(16) unsigned char smem[53760];
  unsigned short* xs2 = (unsigned short*)smem;
  float* sWf = (float*)(smem + 41472);
  unsigned short* sWA = (unsigned short*)(smem + 47616);
  __shared__ float sB[48];

  // ---- phase 1: fold BN into W (f32) + bias; stage x tile as bf16 ----
  for (int idx = tid; idx < 1536; idx += 512) {
    int n = idx >> 9, ch = (idx >> 5) & 15;
    float inv = gq[n * 16 + ch] * rsqrtf(vq[n * 16 + ch] + EPSF);
    if (n == 1) inv *= RS512;
    sWf[idx] = Wq[idx] * inv;  // [n][ch][c] pitch 32
  }
  if (tid < 48) {
    int n = tid >> 4;
    float inv = gq[tid] * rsqrtf(vq[tid] + EPSF);
    float bb = (bq[tid] - mq[tid]) * inv + beq[tid];
    if (n == 1) bb *= RS512;
    sB[tid] = bb;
  }
  {  // x[b, c, f, t0..t0+15] -> xs2[f][t][c], float4 over t
    int tq = tid & 3, rq = tid >> 2;
    const float* xb = x + (size_t)b * 1024 * 4000 + t0 + (tq << 2);
    for (int rr = rq; rr < 1024; rr += 128) {
      float4 f = *(const float4*)(xb + (size_t)rr * 4000);
      const int cc = rr >> 5, fch = rr & 31;
      unsigned short* dst = xs2 + fch * 648 + (tq << 2) * 40 + cc;
      dst[0] = f2bf(f.x);
      dst[40] = f2bf(f.y);
      dst[80] = f2bf(f.z);
      dst[120] = f2bf(f.w);
    }
  }
  __syncthreads();

  // ---- phase 2: build split-precision A fragments ----
  // sWA[slot = n*2+hl][lane][j] = (hl? lo : hi) of W'[n][ch=lane&15][c=(lane>>4)*8+j]
  for (int a = tid; a < 3072; a += 512) {
    int j = a & 7, l = (a >> 3) & 63, slot = a >> 9;
    int n = slot >> 1, hl = slot & 1;
    int ch = l & 15, cc = ((l >> 4) << 3) + j;
    float wf = sWf[(n * 16 + ch) * 32 + cc];
    unsigned short hi = f2bf(wf);
    if (hl) {
      float hif = __uint_as_float((unsigned int)hi << 16);
      sWA[a] = f2bf(wf - hif);
    } else {
      sWA[a] = hi;
    }
  }
  __syncthreads();

  // ---- phase 3: MFMA compute ----
  const int lane = tid & 63, w = tid >> 6;
  const int tl = lane & 15, qd = lane >> 4;
  const float aQ = aq[0], aK = aq[1], aV = aq[2];

  bf16x8 Af[3][2];
#pragma unroll
  for (int n = 0; n < 3; ++n)
#pragma unroll
    for (int hl = 0; hl < 2; ++hl)
      Af[n][hl] = *(const bf16x8*)(sWA + ((((n << 1) + hl) << 6) + lane) * 8);

  floatx4 acc[3][4];
#pragma unroll
  for (int n = 0; n < 3; ++n)
#pragma unroll
    for (int ff = 0; ff < 4; ++ff) {
      acc[n][ff][0] = 0.f; acc[n][ff][1] = 0.f;
      acc[n][ff][2] = 0.f; acc[n][ff][3] = 0.f;
    }

#pragma unroll
  for (int ff = 0; ff < 4; ++ff) {
    const int f = (w << 2) + ff;
    // B[k][t]: lane holds x[c = qd*8..+7][f][t = tl]
    bf16x8 xb = *(const bf16x8*)(xs2 + f * 648 + tl * 40 + (qd << 3));
#pragma unroll
    for (int n = 0; n < 3; ++n) {
      acc[n][ff] = __builtin_amdgcn_mfma_f32_16x16x32_bf16(Af[n][0], xb, acc[n][ff], 0, 0, 0);
      acc[n][ff] = __builtin_amdgcn_mfma_f32_16x16x32_bf16(Af[n][1], xb, acc[n][ff], 0, 0, 0);
    }
  }
  __syncthreads();  // done reading xs2/sWA -> overlay out-staging

  // ---- epilogue: bias + PReLU + bf16, transpose via LDS, coalesced store ---
  unsigned short* oQ = (unsigned short*)smem;     // [16 t][520]
  unsigned short* oK = oQ + 16 * 520;             // [16 t][520]
  unsigned short* oV = oK + 16 * 520;             // [512 d][18]
#pragma unroll
  for (int n = 0; n < 3; ++n) {
    const float sl = (n == 0) ? aQ : ((n == 1) ? aK : aV);
#pragma unroll
    for (int ff = 0; ff < 4; ++ff) {
      const int f = (w << 2) + ff;
#pragma unroll
      for (int rr = 0; rr < 4; ++rr) {
        const int ch = (qd << 2) + rr;
        float v = acc[n][ff][rr] + sB[n * 16 + ch];
        v = v > 0.f ? v : sl * v;
        unsigned short us = f2bf(v);
        const int d = (ch << 5) + f;
        if (n == 0) oQ[tl * 520 + d] = us;
        else if (n == 1) oK[tl * 520 + d] = us;
        else oV[d * 18 + tl] = us;
      }
    }
  }
  __syncthreads();

  for (int i = tid; i < 1024; i += 512) {  // Q,K: 16B-coalesced
    int t = i >> 6, u = i & 63;
    *(uintx4*)(Q + (size_t)(b * 4000 + t0 + t) * 512 + u * 8) =
        *(const uintx4*)(oQ + t * 520 + u * 8);
    *(uintx4*)(K + (size_t)(b * 4000 + t0 + t) * 512 + u * 8) =
        *(const uintx4*)(oK + t * 520 + u * 8);
  }
  {
    const int st = t0 >> 5;
    const int toff = t0 & 16;
    unsigned short* vt = V + ((size_t)(b * 125 + st) * 512) * 32 + toff;
    for (int i = tid; i < 4096; i += 512) {
      int d = i >> 3, u = i & 7;
      unsigned int w2 = *(unsigned int*)&oV[d * 18 + 2 * u];
      ((unsigned int*)(vt + d * 32))[u] = w2;
    }
  }
}

// ---------------- Kernel 2: LDS-staged sigmoid-attention + enc ConvBlock ----
// (verbatim R3: 8 waves x 16q, d-split PV, double-buffered gll staging)
__global__ __launch_bounds__(512, 2) void attn_kernel(
    const float* __restrict__ x,
    const float* __restrict__ encW, const float* __restrict__ encb,
    const float* __restrict__ encg, const float* __restrict__ encbe,
    const float* __restrict__ encm, const float* __restrict__ encv,
    const float* __restrict__ enca,
    const unsigned short* __restrict__ Q, const unsigned short* __restrict__ K,
    const unsigned short* __restrict__ V, float* __restrict__ out) {
  const int tid = threadIdx.x;
  const int lane = tid & 63;
  const int w = tid >> 6;
  const int b = blockIdx.x >> 5;           // 8 b * 32 blocks
  const int bt0 = (blockIdx.x & 31) << 7;  // 0..3968
  const int t0 = bt0 + (w << 4);
  const bool active = t0 < 4000;
  const int c = lane & 15, qd = lane >> 4;

  // LDS map: [Ks 2x33280B][Vs 2x32768B][Pb 10240B] = 142336 B.
  // Eb (f32 [64][516] = 132096 B) overlays Ks+Vs after the tile loop.
  __shared__ __align__(16) unsigned char smem[142336];
  unsigned short* Ksb = (unsigned short*)smem;   // [2][32*520] rows padded
  unsigned short* Vsb = Ksb + 2 * 16640;         // [2][512*32] granule-permuted
  unsigned short* Pb = Vsb + 2 * 16384;          // [128][40] bf16, pitch 80 B
  float* Eb = (float*)smem;                      // [64][516]

  // zero P rows once (covers q-groups of inactive tail waves)
  for (int i = tid; i < 2560; i += 512) ((unsigned int*)Pb)[i] = 0u;

  // Q fragments for this wave's 16 tokens (B operand of S-mfma)
  bf16x8 qf[16];
  {
    const int tq = active ? t0 : 0;
    const unsigned short* qp = Q + (size_t)(b * 4000 + tq + c) * 512 + qd * 8;
#pragma unroll
    for (int ks = 0; ks < 16; ++ks) qf[ks] = *(const bf16x8*)(qp + ks * 32);
  }

  floatx4 acc[4][8];  // [md within slice][q-sub]
#pragma unroll
  for (int m = 0; m < 4; ++m)
#pragma unroll
    for (int q2 = 0; q2 < 8; ++q2) {
      acc[m][q2][0] = 0.f; acc[m][q2][1] = 0.f;
      acc[m][q2][2] = 0.f; acc[m][q2][3] = 0.f;
    }

  const unsigned short* Kb = K + (size_t)b * 4000 * 512;
  const unsigned short* Vb = V + (size_t)b * 125 * 16384;

  // wave w stages K rows 4w..4w+3 (1024 B each) and V chunks 4w..4w+3
  const int r0 = w << 2;
  const int lby = lane * 8;  // 16B per lane, in shorts
  // V source swizzle (verified R1/R2): phys granule l sources logical
  // l ^ (((l>>2)&7) ^ ((l>>4)&1)); read side uses logical^((logical>>2)&7).
  const int vmask = ((lane >> 2) & 7) ^ ((lane >> 4) & 1);
  const int vsw = (lane ^ vmask) << 3;  // shorts within 1024B chunk

  auto stage = [&](int buf, int it) {
    const unsigned short* kg = Kb + (size_t)it * 16384;
    const unsigned short* vg = Vb + (size_t)it * 16384;
    unsigned short* kd = Ksb + buf * 16640;
    unsigned short* vd = Vsb + buf * 16384;
#pragma unroll
    for (int r = 0; r < 4; ++r) {
      gll16(kg + (size_t)((r0 + r) << 9) + lby, kd + (r0 + r) * 520);
      gll16(vg + (size_t)((r0 + r) << 9) + vsw, vd + ((r0 + r) << 9));
    }
  };

  stage(0, 0);
  int cur = 0;

#pragma unroll 1
  for (int it = 0; it < 125; ++it) {
    // drain this wave's gll, then barrier: buf[cur] staged for everyone, and
    // everyone finished last iter's PV (P and prev LDS reads done).
    asm volatile("s_waitcnt vmcnt(0)" ::: "memory");
    __syncthreads();
    if (it + 1 < 125) stage(cur ^ 1, it + 1);  // in flight across compute

    if (active) {  // ---- S-phase: S = K·Q^T for own 16 q, full 32 s ----
      floatx4 sa0, sa1;
      sa0[0] = sa0[1] = sa0[2] = sa0[3] = 0.f;
      sa1 = sa0;
      const unsigned short* kp = Ksb + cur * 16640 + c * 520 + qd * 8;
      __builtin_amdgcn_s_setprio(1);
#pragma unroll
      for (int ks = 0; ks < 16; ++ks) {
        bf16x8 k0 = *(const bf16x8*)(kp + ks * 32);
        bf16x8 k1 = *(const bf16x8*)(kp + 16 * 520 + ks * 32);
        sa0 = __builtin_amdgcn_mfma_f32_16x16x32_bf16(k0, qf[ks], sa0, 0, 0, 0);
        sa1 = __builtin_amdgcn_mfma_f32_16x16x32_bf16(k1, qf[ks], sa1, 0, 0, 0);
      }
      __builtin_amdgcn_s_setprio(0);
      // sigmoid -> packed bf16 -> P[q = w*16+c][s] (lane holds s = qd*4+r, +16)
      float p0 = __builtin_amdgcn_rcpf(1.f + __expf(-sa0[0]));
      float p1 = __builtin_amdgcn_rcpf(1.f + __expf(-sa0[1]));
      float p2 = __builtin_amdgcn_rcpf(1.f + __expf(-sa0[2]));
      float p3 = __builtin_amdgcn_rcpf(1.f + __expf(-sa0[3]));
      float p4 = __builtin_amdgcn_rcpf(1.f + __expf(-sa1[0]));
      float p5 = __builtin_amdgcn_rcpf(1.f + __expf(-sa1[1]));
      float p6 = __builtin_amdgcn_rcpf(1.f + __expf(-sa1[2]));
      float p7 = __builtin_amdgcn_rcpf(1.f + __expf(-sa1[3]));
      unsigned short* pw = Pb + ((w << 4) + c) * 40 + (qd << 2);
      uint2 pa, pb2;
      pa.x = (unsigned int)f2bf(p0) | ((unsigned int)f2bf(p1) << 16);
      pa.y = (unsigned int)f2bf(p2) | ((unsigned int)f2bf(p3) << 16);
      pb2.x = (unsigned int)f2bf(p4) | ((unsigned int)f2bf(p5) << 16);
      pb2.y = (unsigned int)f2bf(p6) | ((unsigned int)f2bf(p7) << 16);
      *(uint2*)pw = pa;
      *(uint2*)(pw + 16) = pb2;
    }
    __syncthreads();  // P complete

    {  // ---- PV-phase (ALL waves): d-slice [64w,64w+64) for all 128 q ----
      const unsigned short* vp =
          Vsb + cur * 16384 + ((((c << 2) | qd) ^ (c & 7)) << 3);
      bf16x8 vf[4];
#pragma unroll
      for (int m = 0; m < 4; ++m)
        vf[m] = *(const bf16x8*)(vp + ((r0 + m) << 9));
      __builtin_amdgcn_s_setprio(1);
#pragma unroll
      for (int h = 0; h < 2; ++h) {
        bf16x8 pf[4];
#pragma unroll
        for (int q2 = 0; q2 < 4; ++q2)
          pf[q2] = *(const bf16x8*)(Pb + ((((h << 2) | q2) << 4) + c) * 40 +
                                    (qd << 3));
#pragma unroll
        for (int m = 0; m < 4; ++m)
#pragma unroll
          for (int q2 = 0; q2 < 4; ++q2)
            acc[m][(h << 2) | q2] = __builtin_amdgcn_mfma_f32_16x16x32_bf16(
                vf[m], pf[q2], acc[m][(h << 2) | q2], 0, 0, 0);
      }
      __builtin_amdgcn_s_setprio(0);
    }
    cur ^= 1;
  }

  __syncthreads();  // all K/V reads done -> Eb may overlay

  // ---- epilogue: exchange d-sliced acc via Eb, then enc+residual ----
  const float ealpha = enca[0];
#pragma unroll
  for (int rnd = 0; rnd < 2; ++rnd) {
    // all waves write their d-slice for q 0..63 (rnd 0) / 64..127 (rnd 1)
#pragma unroll
    for (int m = 0; m < 4; ++m)
#pragma unroll
      for (int q2 = 0; q2 < 4; ++q2)
        *(floatx4*)&Eb[((q2 << 4) + c) * 516 + (w << 6) + (m << 4) +
                       (qd << 2)] = acc[m][(rnd << 2) | q2];
    __syncthreads();
    if ((w >> 2) == rnd && active) {
      const float* er = Eb + (((w & 3) << 4) + c) * 516;
#pragma unroll
      for (int hi = 0; hi < 2; ++hi) {
        floatx4 sh[16];
#pragma unroll
        for (int i = 0; i < 16; ++i)
          sh[i] = *(const floatx4*)&er[(i << 5) + (hi << 4) + (qd << 2)];
#pragma unroll 1
        for (int o = 0; o < 32; ++o) {
          float inv = encg[o] * rsqrtf(encv[o] + EPSF);
          float bfo = (encb[o] - encm[o]) * inv + encbe[o];
          float e0 = 0.f, e1 = 0.f, e2 = 0.f, e3 = 0.f;
#pragma unroll
          for (int i = 0; i < 16; ++i) {
            float wi = encW[(o << 4) + i];
            e0 += wi * sh[i][0]; e1 += wi * sh[i][1];
            e2 += wi * sh[i][2]; e3 += wi * sh[i][3];
          }
          float ee[4] = {e0, e1, e2, e3};
#pragma unroll
          for (int rr = 0; rr < 4; ++rr) {
            float e = ee[rr] * inv + bfo;
            e = e > 0.f ? e : ealpha * e;
            int fq = (qd << 2) + rr + (hi << 4);
            size_t idx = ((size_t)((b << 5) + o) * 32 + fq) * 4000 + t0 + c;
            out[idx] = e + x[idx];
          }
        }
      }
    }
    __syncthreads();
  }
}

extern "C" void kernel_launch(void* const* d_in, const int* in_sizes, int n_in,
                              void* d_out, int out_size, void* d_ws,
                              size_t ws_size, hipStream_t stream) {
  const float* x = (const float*)d_in[0];
  unsigned short* Q = (unsigned short*)d_ws;
  unsigned short* K = Q + (size_t)8 * 4000 * 512;
  unsigned short* V = K + (size_t)8 * 4000 * 512;

  dim3 g1(250, 8);
  qkv_kernel<<<g1, 512, 0, stream>>>(
      x, (const float*)d_in[1], (const float*)d_in[2], (const float*)d_in[3],
      (const float*)d_in[4], (const float*)d_in[5], (const float*)d_in[6],
      (const float*)d_in[7], Q, K, V);

  attn_kernel<<<dim3(256), 512, 0, stream>>>(
      x, (const float*)d_in[8], (const float*)d_in[9], (const float*)d_in[10],
      (const float*)d_in[11], (const float*)d_in[12], (const float*)d_in[13],
      (const float*)d_in[14], Q, K, V, (float*)d_out);
}